// Round 1
// baseline (75.007 us; speedup 1.0000x reference)
//
#include <hip/hip_runtime.h>
#include <math.h>

#define SZ 256
#define KPTS 64
#define K_SIGN 100000.0f
#define EPS_C 1e-5f
#define INV_2PI 0.15915494309189535f

// Kernel 1: compute prod = winding * min_dist for every pixel, and the global max.
// grid = 4 * 256 blocks (one block = one (bn, row i)), block = 256 threads (one per col j).
__global__ __launch_bounds__(256) void contour_prod_kernel(
    const float* __restrict__ contour,   // [4][64][2]
    float* __restrict__ out,             // [4][256][256] (unnormalized prod)
    unsigned int* __restrict__ gmax)     // 1 slot, float-as-uint (non-negative)
{
    __shared__ float cx[KPTS];
    __shared__ float cy[KPTS];

    const int bn = blockIdx.x >> 8;      // 0..3
    const int i  = blockIdx.x & 255;     // row
    const int j  = threadIdx.x;          // col

    if (threadIdx.x < KPTS) {
        cx[threadIdx.x] = contour[(bn * KPTS + threadIdx.x) * 2 + 0];
        cy[threadIdx.x] = contour[(bn * KPTS + threadIdx.x) * 2 + 1];
    }
    __syncthreads();

    const float mx = (float)i * (1.0f / (float)SZ);
    const float my = (float)j * (1.0f / (float)SZ);

    // diff[0], kept for the wrap-around final segment
    const float dx0 = cx[0] - mx;
    const float dy0 = cy[0] - my;
    const float n0  = sqrtf(dx0 * dx0 + dy0 * dy0);

    float dxc = dx0, dyc = dy0, nc = n0;
    float acc  = 0.0f;
    float minn = n0;

    #pragma unroll 4
    for (int k = 0; k < KPTS; ++k) {
        float dxn, dyn, nn;
        if (k == KPTS - 1) {
            dxn = dx0; dyn = dy0; nn = n0;
        } else {
            dxn = cx[k + 1] - mx;
            dyn = cy[k + 1] - my;
            nn  = sqrtf(dxn * dxn + dyn * dyn);
        }

        const float cross = dyc * dxn - dxc * dyn;
        const float sgn   = tanhf(K_SIGN * cross);

        const float nd  = fmaxf(nc, EPS_C);
        const float nr  = fmaxf(nn, EPS_C);
        const float dot = dxc * dxn + dyc * dyn;
        float cosang = dot / (nd * nr);
        cosang = fminf(fmaxf(cosang, -1.0f + EPS_C), 1.0f - EPS_C);
        const float ang = acosf(cosang);

        acc += sgn * ang;
        minn = fminf(minn, nn);

        dxc = dxn; dyc = dyn; nc = nn;
    }

    const float prod = fabsf(acc) * INV_2PI * minn;
    out[((bn << 8) + i) * SZ + j] = prod;

    // wave-level max reduction (64 lanes), then one atomic per wave
    float wmax = prod;
    #pragma unroll
    for (int off = 32; off > 0; off >>= 1)
        wmax = fmaxf(wmax, __shfl_down(wmax, off, 64));
    if ((threadIdx.x & 63) == 0)
        atomicMax(gmax, __float_as_uint(wmax));   // valid: prod >= 0
}

// Kernel 2: divide by the global max, in place.
__global__ __launch_bounds__(256) void contour_norm_kernel(
    float* __restrict__ out,
    const unsigned int* __restrict__ gmax)
{
    const float maxv = __uint_as_float(*gmax);
    const int idx = blockIdx.x * blockDim.x + threadIdx.x;
    out[idx] = out[idx] / maxv;
}

extern "C" void kernel_launch(void* const* d_in, const int* in_sizes, int n_in,
                              void* d_out, int out_size, void* d_ws, size_t ws_size,
                              hipStream_t stream)
{
    const float* contour = (const float*)d_in[0];   // [2][2][64][2] fp32
    float* out = (float*)d_out;                     // [2][2][256][256] fp32
    unsigned int* gmax = (unsigned int*)d_ws;

    hipMemsetAsync(d_ws, 0, sizeof(unsigned int), stream);

    contour_prod_kernel<<<4 * SZ, SZ, 0, stream>>>(contour, out, gmax);
    contour_norm_kernel<<<out_size / 256, 256, 0, stream>>>(out, gmax);
}

// Round 2
// 64.602 us; speedup vs baseline: 1.1611x; 1.1611x over previous
//
#include <hip/hip_runtime.h>
#include <math.h>

#define SZ 256
#define KPTS 64
#define K_SIGN 100000.0f
#define EPS_C 1e-5f
#define INV_2PI 0.15915494309189535f
#define PI_F 3.14159265358979323846f

__device__ __forceinline__ float fast_rcp(float x)  { return __builtin_amdgcn_rcpf(x); }
__device__ __forceinline__ float fast_sqrt(float x) { return __builtin_amdgcn_sqrtf(x); }

// tanh(K*cross) with hardware exp; exact enough (~1e-7) vs libm tanhf.
__device__ __forceinline__ float fast_tanh_big(float x) {
    // tanh(x) = 1 - 2/(exp(2x)+1); exp(+inf)=inf -> 1, exp(-inf)=0 -> -1 (no NaN).
    float t = __expf(2.0f * x);
    return fmaf(-2.0f, fast_rcp(t + 1.0f), 1.0f);
}

// acos approximation (Abramowitz-Stegun 4.4.45), max err ~6.7e-5 rad.
__device__ __forceinline__ float fast_acos(float x) {
    float ax = fabsf(x);
    float s  = fast_sqrt(1.0f - ax);
    float p  = s * fmaf(ax, fmaf(ax, fmaf(ax, -0.0187292994f, 0.0742610037f),
                                  -0.2121143937f), 1.5707288f);
    return (x >= 0.0f) ? p : (PI_F - p);
}

// Kernel 1: prod = winding * min_dist per pixel, plus global max via atomic.
// grid = 4*256 blocks (one block = (bn, row i)), block = 256 threads (col j).
__global__ __launch_bounds__(256) void contour_prod_kernel(
    const float* __restrict__ contour,   // [4][64][2]
    float* __restrict__ out,             // [4][256][256] (unnormalized)
    unsigned int* __restrict__ gmax)     // float-as-uint, non-negative
{
    __shared__ float cx[KPTS + 1];
    __shared__ float cy[KPTS + 1];

    const int bn = blockIdx.x >> 8;
    const int i  = blockIdx.x & 255;
    const int j  = threadIdx.x;

    if (threadIdx.x < KPTS) {
        float x = contour[(bn * KPTS + threadIdx.x) * 2 + 0];
        float y = contour[(bn * KPTS + threadIdx.x) * 2 + 1];
        cx[threadIdx.x] = x;
        cy[threadIdx.x] = y;
        if (threadIdx.x == 0) { cx[KPTS] = x; cy[KPTS] = y; }  // wraparound dup
    }
    __syncthreads();

    const float mx = (float)i * (1.0f / (float)SZ);
    const float my = (float)j * (1.0f / (float)SZ);

    float dxc = cx[0] - mx;
    float dyc = cy[0] - my;
    float nc  = fast_sqrt(fmaf(dxc, dxc, dyc * dyc));

    float acc  = 0.0f;
    float minn = nc;

    #pragma unroll 8
    for (int k = 0; k < KPTS; ++k) {
        const float dxn = cx[k + 1] - mx;
        const float dyn = cy[k + 1] - my;
        const float nn  = fast_sqrt(fmaf(dxn, dxn, dyn * dyn));

        const float cross = dyc * dxn - dxc * dyn;
        const float sgn   = fast_tanh_big(K_SIGN * cross);

        const float nd  = fmaxf(nc, EPS_C);
        const float nr  = fmaxf(nn, EPS_C);
        const float dot = fmaf(dxc, dxn, dyc * dyn);
        float cosang = dot * fast_rcp(nd * nr);
        cosang = fminf(fmaxf(cosang, -1.0f + EPS_C), 1.0f - EPS_C);  // -> v_med3
        const float ang = fast_acos(cosang);

        acc  = fmaf(sgn, ang, acc);
        minn = fminf(minn, nn);

        dxc = dxn; dyc = dyn; nc = nn;
    }

    const float prod = fabsf(acc) * INV_2PI * minn;
    out[((bn << 8) + i) * SZ + j] = prod;

    float wmax = prod;
    #pragma unroll
    for (int off = 32; off > 0; off >>= 1)
        wmax = fmaxf(wmax, __shfl_down(wmax, off, 64));
    if ((threadIdx.x & 63) == 0)
        atomicMax(gmax, __float_as_uint(wmax));
}

// Kernel 2: divide by global max, in place.
__global__ __launch_bounds__(256) void contour_norm_kernel(
    float* __restrict__ out,
    const unsigned int* __restrict__ gmax)
{
    const float maxv = __uint_as_float(*gmax);
    const int idx = blockIdx.x * blockDim.x + threadIdx.x;
    out[idx] = out[idx] / maxv;
}

extern "C" void kernel_launch(void* const* d_in, const int* in_sizes, int n_in,
                              void* d_out, int out_size, void* d_ws, size_t ws_size,
                              hipStream_t stream)
{
    const float* contour = (const float*)d_in[0];   // [2][2][64][2] fp32
    float* out = (float*)d_out;                     // [2][2][256][256] fp32
    unsigned int* gmax = (unsigned int*)d_ws;

    hipMemsetAsync(d_ws, 0, sizeof(unsigned int), stream);

    contour_prod_kernel<<<4 * SZ, SZ, 0, stream>>>(contour, out, gmax);
    contour_norm_kernel<<<out_size / 256, 256, 0, stream>>>(out, gmax);
}

// Round 3
// 60.920 us; speedup vs baseline: 1.2312x; 1.0604x over previous
//
#include <hip/hip_runtime.h>
#include <math.h>

#define SZ 256
#define KPTS 64
#define GROUPS 4
#define SEGS_PER (KPTS / GROUPS)   // 16 segments per thread
#define K_SIGN 100000.0f
#define EPS_C 1e-5f
#define INV_2PI 0.15915494309189535f
#define PI_F 3.14159265358979323846f

__device__ __forceinline__ float fast_rcp(float x)  { return __builtin_amdgcn_rcpf(x); }
__device__ __forceinline__ float fast_sqrt(float x) { return __builtin_amdgcn_sqrtf(x); }
__device__ __forceinline__ float fast_rsq(float x)  { return __builtin_amdgcn_rsqf(x); }

// tanh(2K*x/2) = 1 - 2/(exp(2Kx)+1); exp(inf)->1, exp(0)->-1, no NaN.
__device__ __forceinline__ float fast_tanh_big(float x2k) {
    float t = __expf(x2k);
    return fmaf(-2.0f, fast_rcp(t + 1.0f), 1.0f);
}

// acos approx (Abramowitz-Stegun 4.4.45), max err ~6.7e-5 rad.
__device__ __forceinline__ float fast_acos(float x) {
    float ax = fabsf(x);
    float s  = fast_sqrt(1.0f - ax);
    float p  = s * fmaf(ax, fmaf(ax, fmaf(ax, -0.0187292994f, 0.0742610037f),
                                  -0.2121143937f), 1.5707288f);
    return (x >= 0.0f) ? p : (PI_F - p);
}

// grid = bn(4) * i(256) * jq(4) = 4096 blocks, block = 256 threads.
// thread t: g = t&3 (segment group, 16 segs), jloc = t>>2 -> pixel j = jq*64+jloc.
__global__ __launch_bounds__(256) void contour_prod_kernel(
    const float* __restrict__ contour,   // [4][64][2]
    float* __restrict__ out,             // [4][256][256] unnormalized
    unsigned int* __restrict__ gmax)
{
    __shared__ float cx[KPTS + 1];
    __shared__ float cy[KPTS + 1];
    __shared__ float wred[4];

    const int blk = blockIdx.x;
    const int jq  = blk & 3;
    const int i   = (blk >> 2) & 255;
    const int bn  = blk >> 10;

    const int t = threadIdx.x;
    if (t < KPTS) {
        float x = contour[(bn * KPTS + t) * 2 + 0];
        float y = contour[(bn * KPTS + t) * 2 + 1];
        cx[t] = x; cy[t] = y;
        if (t == 0) { cx[KPTS] = x; cy[KPTS] = y; }   // wraparound dup
    }
    __syncthreads();

    const int g    = t & 3;
    const int jloc = t >> 2;
    const int j    = (jq << 6) + jloc;

    const float mx = (float)i * (1.0f / (float)SZ);
    const float my = (float)j * (1.0f / (float)SZ);

    const int base = g * SEGS_PER;

    float dxc  = cx[base] - mx;
    float dyc  = cy[base] - my;
    float n2c  = fmaf(dxc, dxc, dyc * dyc);
    float invc = fast_rsq(n2c);
    float minn = n2c * invc;            // |diff_base|
    float acc  = 0.0f;

    #pragma unroll
    for (int kk = 0; kk < SEGS_PER; ++kk) {
        const float dxn  = cx[base + kk + 1] - mx;
        const float dyn  = cy[base + kk + 1] - my;
        const float n2n  = fmaf(dxn, dxn, dyn * dyn);
        const float invn = fast_rsq(n2n);
        const float nn   = n2n * invn;
        minn = fminf(minn, nn);

        const float cross = dyc * dxn - dxc * dyn;
        const float sgn   = fast_tanh_big((2.0f * K_SIGN) * cross);

        const float dot = fmaf(dxc, dxn, dyc * dyn);
        float cosang = dot * invc * invn;
        cosang = fminf(fmaxf(cosang, -1.0f + EPS_C), 1.0f - EPS_C);  // v_med3
        const float ang = fast_acos(cosang);

        acc = fmaf(sgn, ang, acc);

        dxc = dxn; dyc = dyn; invc = invn;
    }

    // combine the 4 segment-groups of this pixel (lanes g=0..3 within 4-lane group)
    acc += __shfl_xor(acc, 1, 64);
    acc += __shfl_xor(acc, 2, 64);
    minn = fminf(minn, __shfl_xor(minn, 1, 64));
    minn = fminf(minn, __shfl_xor(minn, 2, 64));

    const float prod = fabsf(acc) * INV_2PI * minn;
    if (g == 0)
        out[((bn << 8) + i) * SZ + j] = prod;

    // block max -> single atomic
    float wmax = prod;
    #pragma unroll
    for (int off = 32; off > 0; off >>= 1)
        wmax = fmaxf(wmax, __shfl_down(wmax, off, 64));
    if ((t & 63) == 0) wred[t >> 6] = wmax;
    __syncthreads();
    if (t == 0) {
        float m = fmaxf(fmaxf(wred[0], wred[1]), fmaxf(wred[2], wred[3]));
        atomicMax(gmax, __float_as_uint(m));   // valid: prod >= 0
    }
}

// normalize in place, float4-vectorized
__global__ __launch_bounds__(256) void contour_norm_kernel(
    float4* __restrict__ out,
    const unsigned int* __restrict__ gmax)
{
    const float maxv = __uint_as_float(*gmax);
    const int idx = blockIdx.x * blockDim.x + threadIdx.x;
    float4 v = out[idx];
    v.x = v.x / maxv;
    v.y = v.y / maxv;
    v.z = v.z / maxv;
    v.w = v.w / maxv;
    out[idx] = v;
}

extern "C" void kernel_launch(void* const* d_in, const int* in_sizes, int n_in,
                              void* d_out, int out_size, void* d_ws, size_t ws_size,
                              hipStream_t stream)
{
    const float* contour = (const float*)d_in[0];   // [2][2][64][2] fp32
    float* out = (float*)d_out;                     // [2][2][256][256] fp32
    unsigned int* gmax = (unsigned int*)d_ws;

    hipMemsetAsync(d_ws, 0, sizeof(unsigned int), stream);

    contour_prod_kernel<<<4 * SZ * GROUPS, SZ, 0, stream>>>(contour, out, gmax);
    contour_norm_kernel<<<out_size / 4 / 256, 256, 0, stream>>>((float4*)out, gmax);
}

// Round 4
// 25.338 us; speedup vs baseline: 2.9603x; 2.4043x over previous
//
#include <hip/hip_runtime.h>
#include <math.h>

#define SZ 256
#define KPTS 64
#define GROUPS 4
#define SEGS_PER (KPTS / GROUPS)   // 16 segments per thread
#define NBLK (4 * SZ * GROUPS)     // 4096 prod blocks
#define K_SIGN 100000.0f
#define EPS_C 1e-5f
#define INV_2PI 0.15915494309189535f
#define PI_F 3.14159265358979323846f

__device__ __forceinline__ float fast_rcp(float x)  { return __builtin_amdgcn_rcpf(x); }
__device__ __forceinline__ float fast_sqrt(float x) { return __builtin_amdgcn_sqrtf(x); }
__device__ __forceinline__ float fast_rsq(float x)  { return __builtin_amdgcn_rsqf(x); }

// tanh via hardware exp: tanh(u) = 1 - 2/(exp(2u)+1); exp(inf)->1, exp(0)->-1.
__device__ __forceinline__ float fast_tanh_big(float x2k) {
    float t = __expf(x2k);
    return fmaf(-2.0f, fast_rcp(t + 1.0f), 1.0f);
}

// acos approx (Abramowitz-Stegun 4.4.45), max err ~6.7e-5 rad.
__device__ __forceinline__ float fast_acos(float x) {
    float ax = fabsf(x);
    float s  = fast_sqrt(1.0f - ax);
    float p  = s * fmaf(ax, fmaf(ax, fmaf(ax, -0.0187292994f, 0.0742610037f),
                                  -0.2121143937f), 1.5707288f);
    return (x >= 0.0f) ? p : (PI_F - p);
}

// d_ws layout: ws[0] = global max (float), ws[1 + blk] = per-block max.

// grid = bn(4) * i(256) * jq(4) = 4096 blocks, block = 256 threads.
// thread t: g = t&3 (segment group of 16), jloc = t>>2 -> pixel j = jq*64+jloc.
__global__ __launch_bounds__(256) void contour_prod_kernel(
    const float* __restrict__ contour,   // [4][64][2]
    float* __restrict__ out,             // [4][256][256] unnormalized
    float* __restrict__ ws)
{
    __shared__ float cx[KPTS + 1];
    __shared__ float cy[KPTS + 1];
    __shared__ float wred[4];

    const int blk = blockIdx.x;
    const int jq  = blk & 3;
    const int i   = (blk >> 2) & 255;
    const int bn  = blk >> 10;

    const int t = threadIdx.x;
    if (t < KPTS) {
        float x = contour[(bn * KPTS + t) * 2 + 0];
        float y = contour[(bn * KPTS + t) * 2 + 1];
        cx[t] = x; cy[t] = y;
        if (t == 0) { cx[KPTS] = x; cy[KPTS] = y; }   // wraparound dup
    }
    __syncthreads();

    const int g    = t & 3;
    const int jloc = t >> 2;
    const int j    = (jq << 6) + jloc;

    const float mx = (float)i * (1.0f / (float)SZ);
    const float my = (float)j * (1.0f / (float)SZ);

    const int base = g * SEGS_PER;

    float dxc  = cx[base] - mx;
    float dyc  = cy[base] - my;
    float n2c  = fmaf(dxc, dxc, dyc * dyc);
    float invc = fast_rsq(n2c);
    float minn = n2c * invc;            // |diff_base|
    float acc  = 0.0f;

    #pragma unroll
    for (int kk = 0; kk < SEGS_PER; ++kk) {
        const float dxn  = cx[base + kk + 1] - mx;
        const float dyn  = cy[base + kk + 1] - my;
        const float n2n  = fmaf(dxn, dxn, dyn * dyn);
        const float invn = fast_rsq(n2n);
        const float nn   = n2n * invn;
        minn = fminf(minn, nn);

        const float cross = dyc * dxn - dxc * dyn;
        const float sgn   = fast_tanh_big((2.0f * K_SIGN) * cross);

        const float dot = fmaf(dxc, dxn, dyc * dyn);
        float cosang = dot * invc * invn;
        cosang = fminf(fmaxf(cosang, -1.0f + EPS_C), 1.0f - EPS_C);  // v_med3
        const float ang = fast_acos(cosang);

        acc = fmaf(sgn, ang, acc);

        dxc = dxn; dyc = dyn; invc = invn;
    }

    // combine the 4 segment-groups of this pixel
    acc += __shfl_xor(acc, 1, 64);
    acc += __shfl_xor(acc, 2, 64);
    minn = fminf(minn, __shfl_xor(minn, 1, 64));
    minn = fminf(minn, __shfl_xor(minn, 2, 64));

    const float prod = fabsf(acc) * INV_2PI * minn;
    if (g == 0)
        out[((bn << 8) + i) * SZ + j] = prod;

    // block max -> plain store (no atomic)
    float wmax = prod;
    #pragma unroll
    for (int off = 32; off > 0; off >>= 1)
        wmax = fmaxf(wmax, __shfl_down(wmax, off, 64));
    if ((t & 63) == 0) wred[t >> 6] = wmax;
    __syncthreads();
    if (t == 0) {
        ws[1 + blk] = fmaxf(fmaxf(wred[0], wred[1]), fmaxf(wred[2], wred[3]));
    }
}

// single block: reduce ws[1..NBLK] -> ws[0]
__global__ __launch_bounds__(256) void contour_reduce_kernel(float* __restrict__ ws)
{
    __shared__ float wred[4];
    const int t = threadIdx.x;
    float m = 0.0f;   // prod >= 0, so 0 is a safe identity
    #pragma unroll
    for (int r = 0; r < NBLK / 256; ++r)
        m = fmaxf(m, ws[1 + t + (r << 8)]);
    #pragma unroll
    for (int off = 32; off > 0; off >>= 1)
        m = fmaxf(m, __shfl_down(m, off, 64));
    if ((t & 63) == 0) wred[t >> 6] = m;
    __syncthreads();
    if (t == 0)
        ws[0] = fmaxf(fmaxf(wred[0], wred[1]), fmaxf(wred[2], wred[3]));
}

// normalize in place, float4-vectorized
__global__ __launch_bounds__(256) void contour_norm_kernel(
    float4* __restrict__ out,
    const float* __restrict__ ws)
{
    const float maxv = ws[0];
    const int idx = blockIdx.x * blockDim.x + threadIdx.x;
    float4 v = out[idx];
    v.x = v.x / maxv;
    v.y = v.y / maxv;
    v.z = v.z / maxv;
    v.w = v.w / maxv;
    out[idx] = v;
}

extern "C" void kernel_launch(void* const* d_in, const int* in_sizes, int n_in,
                              void* d_out, int out_size, void* d_ws, size_t ws_size,
                              hipStream_t stream)
{
    const float* contour = (const float*)d_in[0];   // [2][2][64][2] fp32
    float* out = (float*)d_out;                     // [2][2][256][256] fp32
    float* ws  = (float*)d_ws;

    contour_prod_kernel<<<NBLK, SZ, 0, stream>>>(contour, out, ws);
    contour_reduce_kernel<<<1, 256, 0, stream>>>(ws);
    contour_norm_kernel<<<out_size / 4 / 256, 256, 0, stream>>>((float4*)out, ws);
}